// Round 19
// baseline (136.456 us; speedup 1.0000x reference)
//
#include <hip/hip_runtime.h>
#include <hip/hip_bf16.h>
#include <stdint.h>

#define NH 12
#define DH 64
#define SEQ 4096
#define DM 768
#define NEGV -1e9f
#define LOG2E 1.4426950408889634f
#define QSCALE 0.1803368801111601f  // 0.125 * log2(e)

using bf16x8 = __attribute__((ext_vector_type(8))) short;
using f32x4  = __attribute__((ext_vector_type(4))) float;

static __device__ __forceinline__ short f2bf(float f) {
  unsigned u = __builtin_bit_cast(unsigned, f);
  u += 0x7fffu + ((u >> 16) & 1u);
  return (short)(u >> 16);
}

// round-half-up bf16 pair pack via v_perm_b32
static __device__ __forceinline__ unsigned pack2bf_rnd(float lo, float hi) {
  unsigned a = __builtin_bit_cast(unsigned, lo) + 0x8000u;
  unsigned b = __builtin_bit_cast(unsigned, hi) + 0x8000u;
  return __builtin_amdgcn_perm(b, a, 0x07060302u);
}

static __device__ __forceinline__ void gload16(const void* g, void* l) {
  __builtin_amdgcn_global_load_lds(
      (const __attribute__((address_space(1))) unsigned*)g,
      (__attribute__((address_space(3))) unsigned*)l, 16, 0, 0);
}

static __device__ __forceinline__ f32x4 mfma16(bf16x8 a, bf16x8 b, f32x4 c) {
  return __builtin_amdgcn_mfma_f32_16x16x32_bf16(a, b, c, 0, 0, 0);
}

#define SBAR() __builtin_amdgcn_sched_barrier(0)
#define WAIT8() asm volatile("s_waitcnt vmcnt(8)" ::: "memory")
#define WAIT6() asm volatile("s_waitcnt vmcnt(6)" ::: "memory")
#define WAIT0() asm volatile("s_waitcnt vmcnt(0)" ::: "memory")
#define HBAR() __builtin_amdgcn_s_barrier()

// ---------------- merged conversion kernel ----------------
__global__ __launch_bounds__(256) void cvt_all(
    const float* __restrict__ X, short* __restrict__ Xb,
    const float* __restrict__ Wq, const float* __restrict__ Wk,
    const float* __restrict__ Wv, const float* __restrict__ Wo,
    short* __restrict__ Wqkv, short* __restrict__ Wob) {
  int i = blockIdx.x * 256 + threadIdx.x;
  const int nx = 8192 * 768 / 4;
  if (i < nx) {
    float4 v = ((const float4*)X)[i];
    short4 o; o.x = f2bf(v.x); o.y = f2bf(v.y); o.z = f2bf(v.z); o.w = f2bf(v.w);
    ((short4*)Xb)[i] = o;
    return;
  }
  i -= nx;
  const int n1 = 2304 * 768 / 4;
  if (i < n1) {
    int e = i * 4;
    int row = e / 768;
    const float* src;
    float sc = 1.0f;
    if (row < 768)       { src = Wq + e; sc = QSCALE; }
    else if (row < 1536) { src = Wk + e - 768 * 768; }
    else                 { src = Wv + e - 1536 * 768; }
    float4 v = *(const float4*)src;
    short4 o; o.x = f2bf(v.x * sc); o.y = f2bf(v.y * sc);
    o.z = f2bf(v.z * sc); o.w = f2bf(v.w * sc);
    ((short4*)Wqkv)[i] = o;
  } else {
    int j = i - n1;
    if (j >= 768 * 768 / 4) return;
    float4 v = ((const float4*)Wo)[j];
    short4 o; o.x = f2bf(v.x); o.y = f2bf(v.y); o.z = f2bf(v.z); o.w = f2bf(v.w);
    ((short4*)Wob)[j] = o;
  }
}

// ======= 128x128 BK=64 2-buffer pipeline (R16) — used by gemm_out =======
#define GEMM_PIPELINE(SM, AG, BG, ACC, LANE, WR, WC)                           \
  {                                                                            \
    const int l15 = (LANE) & 15, gw = (LANE) >> 4;                             \
    const int s_ = (l15 >> 1) & 3;                                             \
    const int NT = 12; /* 768/64 */                                            \
    auto stage = [&](int t) {                                                  \
      short* ab = (SM) + ((t & 1) << 13);                                      \
      short* bb = (SM) + 16384 + ((t & 1) << 13);                              \
      int kt = t << 6;                                                         \
      gload16((AG) + kt, ab + ldst);                                           \
      gload16((AG) + kt + 32 * 768, ab + ldst + 2048);                         \
      gload16((AG) + kt + 64 * 768, ab + ldst + 4096);                         \
      gload16((AG) + kt + 96 * 768, ab + ldst + 6144);                         \
      gload16((BG) + kt, bb + ldst);                                           \
      gload16((BG) + kt + 32 * 768, bb + ldst + 2048);                         \
      gload16((BG) + kt + 64 * 768, bb + ldst + 4096);                         \
      gload16((BG) + kt + 96 * 768, bb + ldst + 6144);                         \
    };                                                                         \
    auto compute = [&](int t) {                                                \
      const short* ab = (SM) + ((t & 1) << 13);                                \
      const short* bb = (SM) + 16384 + ((t & 1) << 13);                        \
      _Pragma("unroll") for (int kk = 0; kk < 2; ++kk) {                       \
        const int fc = (((kk << 2) + (gw ^ s_)) << 3);                         \
        bf16x8 af[4], bf[4];                                                   \
        _Pragma("unroll") for (int mi = 0; mi < 4; ++mi)                       \
            af[mi] = *(const bf16x8*)(ab + ((WR) + mi * 16 + l15) * 64 + fc);  \
        _Pragma("unroll") for (int ni = 0; ni < 4; ++ni)                       \
            bf[ni] = *(const bf16x8*)(bb + ((WC) + ni * 16 + l15) * 64 + fc);  \
        __builtin_amdgcn_s_setprio(1);                                         \
        _Pragma("unroll") for (int mi = 0; mi < 4; ++mi)                       \
            _Pragma("unroll") for (int ni = 0; ni < 4; ++ni)                   \
                ACC[mi][ni] = mfma16(af[mi], bf[ni], ACC[mi][ni]);             \
        __builtin_amdgcn_s_setprio(0);                                         \
      }                                                                        \
    };                                                                         \
    stage(0); stage(1);                                                        \
    SBAR();                                                                    \
    _Pragma("unroll 1") for (int i = 0; i < NT; ++i) {                         \
      SBAR();                                                                  \
      if (i < NT - 1) { WAIT8(); } else { WAIT0(); }                           \
      HBAR(); SBAR();                                                          \
      compute(i);                                                              \
      SBAR(); HBAR();                                                          \
      if (i + 2 < NT) stage(i + 2);                                            \
    }                                                                          \
  }

// ---------------- QKV projection GEMM: 256x128 tile, 512 threads ----------
// Grid 576 = 8 XCD x (4 m x 18 n). LDS 96KB (2buf A 256x64 + B 128x64).
// Stage = 6 loads/thread; counted vmcnt(6); 12 K-iters.
__global__ __launch_bounds__(512) void gemm_qkv(
    const short* __restrict__ Xb, const short* __restrict__ Wqkv,
    const float* __restrict__ bq, const float* __restrict__ bk,
    const float* __restrict__ bv,
    short* __restrict__ qO, short* __restrict__ kO, short* __restrict__ vT) {
  __shared__ __align__(16) short sm[49152];
  const int tid = threadIdx.x, lane = tid & 63, wid = tid >> 6;
  const int xcd = blockIdx.x & 7, kk = blockIdx.x >> 3;  // kk in [0,72)
  const int m0 = (xcd * 4 + (kk & 3)) * 256;
  const int n0 = (kk >> 2) * 128;
  const int wrow = (wid >> 1) * 64, wcol = (wid & 1) * 64;
  const int l15 = lane & 15, gw = lane >> 4;
  const int s_ = (l15 >> 1) & 3;
  const int ldst = tid * 8;

  // precomputed staging offsets (4 A passes, 2 B passes), swizzled source
  int aoff[4], boff[2];
#pragma unroll
  for (int p = 0; p < 4; ++p) {
    int e = p * 4096 + ldst;
    int row = e >> 6;
    int gs = ((e >> 3) & 7) ^ ((row >> 1) & 3);
    aoff[p] = row * 768 + (gs << 3);
  }
#pragma unroll
  for (int p = 0; p < 2; ++p) {
    int e = p * 4096 + ldst;
    int row = e >> 6;
    int gs = ((e >> 3) & 7) ^ ((row >> 1) & 3);
    boff[p] = row * 768 + (gs << 3);
  }
  const short* Ag = Xb + (size_t)m0 * 768;
  const short* Bg = Wqkv + (size_t)n0 * 768;

  const int src = n0 / 768;  // 0=q 1=k 2=v
  const int nloc = n0 % 768;
  float bias[4];
#pragma unroll
  for (int ni = 0; ni < 4; ++ni) {
    int c = nloc + wcol + ni * 16 + l15;
    bias[ni] = (src == 0) ? bq[c] * QSCALE : (src == 1) ? bk[c] : bv[c];
  }
  WAIT0(); SBAR();

  auto stage = [&](int t) {
    short* ab = sm + ((t & 1) << 14);
    short* bb = sm + 32768 + ((t & 1) << 13);
    int kt = t << 6;
#pragma unroll
    for (int p = 0; p < 4; ++p) gload16(Ag + aoff[p] + kt, ab + p * 4096 + ldst);
#pragma unroll
    for (int p = 0; p < 2; ++p) gload16(Bg + boff[p] + kt, bb + p * 4096 + ldst);
  };
  f32x4 acc[4][4] = {};
  auto compute = [&](int t) {
    const short* ab = sm + ((t & 1) << 14);
    const short* bb = sm + 32768 + ((t & 1) << 13);
#pragma unroll
    for (int kk2 = 0; kk2 < 2; ++kk2) {
      const int fc = (((kk2 << 2) + (gw ^ s_)) << 3);
      bf16x8 af[4], bf[4];
#pragma unroll
      for (int mi = 0; mi < 4; ++mi)
        af[mi] = *(const bf16x8*)(ab + (wrow + mi * 16 + l15) * 64 + fc);
#pragma unroll
      for (int ni = 0; ni < 4; ++ni)
        bf[ni] = *(const bf16x8*)(bb + (wcol + ni * 16 + l15) * 64 + fc);
      __builtin_amdgcn_s_setprio(1);
#pragma unroll
      for (int mi = 0; mi < 4; ++mi)
#pragma unroll
        for (int ni = 0; ni < 4; ++ni)
          acc[mi][ni] = mfma16(af[mi], bf[ni], acc[mi][ni]);
      __builtin_amdgcn_s_setprio(0);
    }
  };

  stage(0); stage(1);
  SBAR();
#pragma unroll 1
  for (int i = 0; i < 12; ++i) {
    SBAR();
    if (i < 11) { WAIT6(); } else { WAIT0(); }
    HBAR(); SBAR();
    compute(i);
    SBAR(); HBAR();
    if (i + 2 < 12) stage(i + 2);
  }

  // epilogue: two 128-row halves (barrier-uniform)
  const int bb_ = m0 >> 12;
  const int s0 = m0 & (SEQ - 1);
  if (src < 2) {
    short* dst = (src == 0) ? qO : kO;
#pragma unroll 1
    for (int h = 0; h < 2; ++h) {
      __syncthreads();
      if ((wrow >> 7) == h) {
#pragma unroll
        for (int mi = 0; mi < 4; ++mi)
#pragma unroll
          for (int ni = 0; ni < 4; ++ni) {
            int row = (wrow & 127) + mi * 16 + ((lane >> 4) << 2);
            int col = wcol + ni * 16 + l15;
#pragma unroll
            for (int r = 0; r < 4; ++r)
              sm[(row + r) * 132 + col] = f2bf(acc[mi][ni][r] + bias[ni]);
          }
      }
      __syncthreads();
      for (int u = tid; u < 8192; u += 512) {
        int r = u >> 6, cp = (u & 63) << 1;
        unsigned val = *(const unsigned*)&sm[r * 132 + cp];
        int c = nloc + cp;
        int hh = c >> 6, d = c & 63;
        *(unsigned*)&dst[(((bb_ * NH + hh) * SEQ) + s0 + h * 128 + r) * DH + d] = val;
      }
    }
  } else {
#pragma unroll 1
    for (int h = 0; h < 2; ++h) {
      __syncthreads();
      if ((wrow >> 7) == h) {
#pragma unroll
        for (int mi = 0; mi < 4; ++mi)
#pragma unroll
          for (int ni = 0; ni < 4; ++ni) {
            int row = (wrow & 127) + mi * 16 + ((lane >> 4) << 2);
            int col = wcol + ni * 16 + l15;
            short4 pk;
            pk.x = f2bf(acc[mi][ni][0] + bias[ni]);
            pk.y = f2bf(acc[mi][ni][1] + bias[ni]);
            pk.z = f2bf(acc[mi][ni][2] + bias[ni]);
            pk.w = f2bf(acc[mi][ni][3] + bias[ni]);
            *(short4*)&sm[col * 132 + row] = pk;
          }
      }
      __syncthreads();
      for (int u = tid; u < 8192; u += 512) {
        int cc = u >> 6, rp = (u & 63) << 1;
        unsigned val = *(const unsigned*)&sm[cc * 132 + rp];
        int c = nloc + cc;
        int hh = c >> 6, d = c & 63;
        *(unsigned*)&vT[(((bb_ * NH + hh) * DH) + d) * SEQ + s0 + h * 128 + rp] = val;
      }
    }
  }
}

// ---------------- sliding-window attention (R18-exact) ----------------
__global__ __launch_bounds__(512, 4) void attn(
    const short* __restrict__ qI, const short* __restrict__ kI,
    const short* __restrict__ vT, const float* __restrict__ amask,
    short* __restrict__ ctx) {
  __shared__ __align__(16) short Ks[128 * 64];
  __shared__ __align__(16) short Vs[64 * 128];
  __shared__ __align__(16) short Ps[8][16 * 132];
  __shared__ __align__(16) float BiasL[768];
  const int tid = threadIdx.x, lane = tid & 63, wid = tid >> 6;
  const int vb_id = (blockIdx.x & 7) * 96 + (blockIdx.x >> 3);
  const int strip = vb_id & 31;
  const int hh = (vb_id >> 5) % 12;
  const int bb = vb_id / 384;
  const int s0 = strip * 128;
  const int n = s0 >> 8;
  const int i0 = s0 & 255;
  const int base = (n - 1) * 256;
  const int bh = bb * NH + hh;
  const int m = lane & 15, hq = lane >> 4;
  const int swz = m & 7;
  const int iw = i0 + (wid << 4);

  const short* qbase = qI + ((size_t)(bh * SEQ) + s0 + (wid << 4)) * DH;
  const bf16x8 aq0 = *(const bf16x8*)(qbase + m * DH + (hq << 3));
  const bf16x8 aq1 = *(const bf16x8*)(qbase + m * DH + 32 + (hq << 3));

  const int kb_s0 = m * 64 + ((hq ^ swz) << 3);
  const int kb_s1 = m * 64 + (((hq + 4) ^ swz) << 3);
  const int vk0 = m * 128 + ((hq ^ swz) << 3);
  const int vk1 = m * 128 + (((hq + 4) ^ swz) << 3);
  const int vk2 = m * 128 + (((hq + 8) ^ swz) << 3);
  const int vk3 = m * 128 + (((hq + 12) ^ swz) << 3);
  short* Pw = Ps[wid];
  const int pwr = m * 132;

  const int e0 = tid * 8, e1 = tid * 8 + 4096;
  const int kj0 = e0 >> 6, kj1 = e1 >> 6;
  const int ksrc0 = kj0 * DH + ((((e0 >> 3) & 7) ^ (kj0 & 7)) << 3);
  const int ksrc1 = kj1 * DH + ((((e1 >> 3) & 7) ^ (kj1 & 7)) << 3);
  const int vd0 = e0 >> 7, vd1 = e1 >> 7;
  const int vsrc0 = vd0 * SEQ + ((((e0 >> 3) & 15) ^ (vd0 & 7)) << 3);
  const int vsrc1 = vd1 * SEQ + ((((e1 >> 3) & 15) ^ (vd1 & 7)) << 3);

  const short* kg0 = kI + (size_t)bh * SEQ * DH;
  const short* vg0 = vT + (size_t)bh * DH * SEQ;

  if (tid < 192) {
    int idx = base + tid * 4;
    idx = idx < 0 ? 0 : (idx > SEQ - 4 ? SEQ - 4 : idx);
    float4 bv = *(const float4*)(amask + bb * SEQ + idx);
    bv.x *= -LOG2E; bv.y *= -LOG2E; bv.z *= -LOG2E; bv.w *= -LOG2E;
    *(float4*)&BiasL[tid * 4] = bv;
  }

  f32x4 acc[4] = {};
  float mrow = -1e30f, lrow = 0.f;

#pragma unroll 1
  for (int c = 0; c < 6; ++c) {
    const int j0 = c << 7;
    const int kpos0 = base + j0;
    if (kpos0 < 0 || kpos0 >= SEQ) continue;
    if (j0 + 127 < i0 || j0 > i0 + 639) continue;

    __syncthreads();
    {
      const short* kb = kg0 + (size_t)kpos0 * DH;
      gload16(kb + ksrc0, (short*)Ks + e0);
      gload16(kb + ksrc1, (short*)Ks + e1);
      const short* vbp = vg0 + kpos0;
      gload16(vbp + vsrc0, (short*)Vs + e0);
      gload16(vbp + vsrc1, (short*)Vs + e1);
    }
    __syncthreads();

    f32x4 sc[8];
    __builtin_amdgcn_s_setprio(1);
#pragma unroll
    for (int jt = 0; jt < 8; ++jt) {
      bf16x8 k0 = *(const bf16x8*)(Ks + jt * 1024 + kb_s0);
      bf16x8 k1 = *(const bf16x8*)(Ks + jt * 1024 + kb_s1);
      f32x4 z = {};
      z = mfma16(k0, aq0, z);
      z = mfma16(k1, aq1, z);
      sc[jt] = z;
    }
    __builtin_amdgcn_s_setprio(0);

    const float* mp = BiasL + j0 + (hq << 2);
    float mn_l = -3e38f;
    const bool interior = (j0 >= iw + 15) && (j0 <= iw + 385);
    if (interior) {
#pragma unroll
      for (int jt = 0; jt < 8; ++jt) {
        float4 b4 = *(const float4*)(mp + jt * 16);
#pragma unroll
        for (int r = 0; r < 4; ++r) {
          float s = sc[jt][r] + (&b4.x)[r];
          sc[jt][r] = s;
          mn_l = fmaxf(mn_l, s);
        }
      }
    } else {
      const int iq = iw + m;
#pragma unroll
      for (int jt = 0; jt < 8; ++jt) {
        float4 b4 = *(const float4*)(mp + jt * 16);
        const int jb = j0 + jt * 16 + (hq << 2);
#pragma unroll
        for (int r = 0; r < 4; ++r) {
          int j = jb + r;
          float s = sc[jt][r] + (&b4.x)[r];
          s = (j >= iq && j <= iq + 512) ? s : NEGV;
          sc[jt][r] = s;
          mn_l = fmaxf(mn_l, s);
        }
      }
    }

    if (__any(mn_l > mrow + 8.0f)) {
      float mn = fmaxf(mrow, mn_l);
      mn = fmaxf(mn, __shfl_xor(mn, 16));
      mn = fmaxf(mn, __shfl_xor(mn, 32));
      const float scl = exp2f(mrow - mn);
      mrow = mn;
      lrow *= scl;
      const float s0r = __shfl(scl, (hq << 2) + 0);
      const float s1r = __shfl(scl, (hq << 2) + 1);
      const float s2r = __shfl(scl, (hq << 2) + 2);
      const float s3r = __shfl(scl, (hq << 2) + 3);
#pragma unroll
      for (int nt = 0; nt < 4; ++nt) {
        acc[nt][0] *= s0r; acc[nt][1] *= s1r;
        acc[nt][2] *= s2r; acc[nt][3] *= s3r;
      }
    }

    float l0 = 0.f;
#pragma unroll
    for (int jt = 0; jt < 8; ++jt) {
      float p0 = exp2f(sc[jt][0] - mrow);
      float p1 = exp2f(sc[jt][1] - mrow);
      float p2 = exp2f(sc[jt][2] - mrow);
      float p3 = exp2f(sc[jt][3] - mrow);
      l0 += (p0 + p1) + (p2 + p3);
      uint2 u;
      u.x = pack2bf_rnd(p0, p1);
      u.y = pack2bf_rnd(p2, p3);
      *(uint2*)(Pw + pwr + jt * 16 + (hq << 2)) = u;
    }
    lrow += l0;

    asm volatile("s_waitcnt lgkmcnt(0)" ::: "memory");
    __builtin_amdgcn_sched_barrier(0);

    __builtin_amdgcn_s_setprio(1);
#pragma unroll
    for (int ks = 0; ks < 4; ++ks) {
      bf16x8 pa = *(const bf16x8*)(Pw + pwr + ks * 32 + (hq << 3));
      const int vkk = (ks == 0) ? vk0 : (ks == 1) ? vk1 : (ks == 2) ? vk2 : vk3;
#pragma unroll
      for (int nt = 0; nt < 4; ++nt) {
        bf16x8 vv = *(const bf16x8*)(Vs + nt * 2048 + vkk);
        acc[nt] = mfma16(pa, vv, acc[nt]);
      }
    }
    __builtin_amdgcn_s_setprio(0);
  }

  lrow += __shfl_xor(lrow, 16);
  lrow += __shfl_xor(lrow, 32);
  const float inv = 1.0f / lrow;
  const float i0r = __shfl(inv, (hq << 2) + 0);
  const float i1r = __shfl(inv, (hq << 2) + 1);
  const float i2r = __shfl(inv, (hq << 2) + 2);
  const float i3r = __shfl(inv, (hq << 2) + 3);
#pragma unroll
  for (int nt = 0; nt < 4; ++nt) {
    Pw[((hq << 2) + 0) * 72 + nt * 16 + m] = f2bf(acc[nt][0] * i0r);
    Pw[((hq << 2) + 1) * 72 + nt * 16 + m] = f2bf(acc[nt][1] * i1r);
    Pw[((hq << 2) + 2) * 72 + nt * 16 + m] = f2bf(acc[nt][2] * i2r);
    Pw[((hq << 2) + 3) * 72 + nt * 16 + m] = f2bf(acc[nt][3] * i3r);
  }
  asm volatile("s_waitcnt lgkmcnt(0)" ::: "memory");
  __builtin_amdgcn_sched_barrier(0);
#pragma unroll
  for (int it = 0; it < 2; ++it) {
    int row = it * 8 + (lane >> 3);
    bf16x8 val = *(const bf16x8*)(Pw + row * 72 + ((lane & 7) << 3));
    *(bf16x8*)(ctx + ((size_t)(bb * SEQ) + s0 + (wid << 4) + row) * DM +
               hh * DH + ((lane & 7) << 3)) = val;
  }
}

// ---------------- output projection GEMM (BK=64 pipelined, R16) -----------
__global__ __launch_bounds__(256) void gemm_out(
    const short* __restrict__ Cb, const short* __restrict__ Wob,
    const float* __restrict__ bo, float* __restrict__ out) {
  __shared__ __align__(16) short sm[32768];
  const int tid = threadIdx.x, lane = tid & 63, wid = tid >> 6;
  const int xcd = blockIdx.x & 7, kk = blockIdx.x >> 3;  // kk in [0,48)
  const int m0 = (xcd * 8 + (kk & 7)) * 128;
  const int n0 = (kk >> 3) * 128;
  const int wr = (wid >> 1) * 64, wc = (wid & 1) * 64;
  const int srow = tid >> 3;
  const int scol = (((tid & 7) ^ ((tid >> 4) & 3)) << 3);
  const short* Ag = Cb + (m0 + srow) * 768 + scol;
  const short* Bg = Wob + (n0 + srow) * 768 + scol;
  const int ldst = tid * 8;

  float bias[4];
#pragma unroll
  for (int ni = 0; ni < 4; ++ni)
    bias[ni] = bo[n0 + wc + ni * 16 + (lane & 15)];
  WAIT0(); SBAR();

  f32x4 acc[4][4] = {};
  GEMM_PIPELINE(sm, Ag, Bg, acc, lane, wr, wc);

#pragma unroll
  for (int mi = 0; mi < 4; ++mi)
#pragma unroll
    for (int ni = 0; ni < 4; ++ni) {
      int row = m0 + wr + mi * 16 + ((lane >> 4) << 2);
      int col = n0 + wc + ni * 16 + (lane & 15);
#pragma unroll
      for (int r = 0; r < 4; ++r)
        out[(row + r) * DM + col] = acc[mi][ni][r] + bias[ni];
    }
}

// ---------------- launcher ----------------
extern "C" void kernel_launch(void* const* d_in, const int* in_sizes, int n_in,
                              void* d_out, int out_size, void* d_ws, size_t ws_size,
                              hipStream_t stream) {
  (void)in_sizes; (void)n_in; (void)out_size; (void)ws_size;
  const float* hs    = (const float*)d_in[0];
  const float* amask = (const float*)d_in[1];
  const float* Wq = (const float*)d_in[2];
  const float* bq = (const float*)d_in[3];
  const float* Wk = (const float*)d_in[4];
  const float* bk = (const float*)d_in[5];
  const float* Wv = (const float*)d_in[6];
  const float* bv = (const float*)d_in[7];
  const float* Wo = (const float*)d_in[8];
  const float* bo = (const float*)d_in[9];
  float* out = (float*)d_out;
  char* ws = (char*)d_ws;
  short* Xb   = (short*)(ws);
  short* Wqkv = (short*)(ws + 12582912);
  short* Wob  = (short*)(ws + 16121856);
  short* qB   = (short*)(ws + 17301504);
  short* kB   = (short*)(ws + 29884416);
  short* vTB  = (short*)(ws + 42467328);
  short* ctx  = Xb;  // Xb dead after gemm_qkv

  cvt_all<<<dim3(8448), dim3(256), 0, stream>>>(hs, Xb, Wq, Wk, Wv, Wo, Wqkv, Wob);
  gemm_qkv<<<dim3(576), dim3(512), 0, stream>>>(Xb, Wqkv, bq, bk, bv, qB, kB, vTB);
  attn<<<dim3(768), dim3(512), 0, stream>>>(qB, kB, vTB, amask, ctx);
  gemm_out<<<dim3(384), dim3(256), 0, stream>>>(ctx, Wob, bo, out);
}

// Round 20
// 123.512 us; speedup vs baseline: 1.1048x; 1.1048x over previous
//
#include <hip/hip_runtime.h>
#include <hip/hip_bf16.h>
#include <stdint.h>

#define NH 12
#define DH 64
#define SEQ 4096
#define DM 768
#define NEGV -1e9f
#define LOG2E 1.4426950408889634f
#define QSCALE 0.1803368801111601f  // 0.125 * log2(e)

using bf16x8 = __attribute__((ext_vector_type(8))) short;
using f32x4  = __attribute__((ext_vector_type(4))) float;

static __device__ __forceinline__ short f2bf(float f) {
  unsigned u = __builtin_bit_cast(unsigned, f);
  u += 0x7fffu + ((u >> 16) & 1u);
  return (short)(u >> 16);
}

// round-half-up bf16 pair pack via v_perm_b32 (3 VALU vs 6 for RNE)
static __device__ __forceinline__ unsigned pack2bf_rnd(float lo, float hi) {
  unsigned a = __builtin_bit_cast(unsigned, lo) + 0x8000u;
  unsigned b = __builtin_bit_cast(unsigned, hi) + 0x8000u;
  return __builtin_amdgcn_perm(b, a, 0x07060302u);
}

static __device__ __forceinline__ void gload16(const void* g, void* l) {
  __builtin_amdgcn_global_load_lds(
      (const __attribute__((address_space(1))) unsigned*)g,
      (__attribute__((address_space(3))) unsigned*)l, 16, 0, 0);
}

static __device__ __forceinline__ f32x4 mfma16(bf16x8 a, bf16x8 b, f32x4 c) {
  return __builtin_amdgcn_mfma_f32_16x16x32_bf16(a, b, c, 0, 0, 0);
}

#define SBAR() __builtin_amdgcn_sched_barrier(0)
#define WAIT8() asm volatile("s_waitcnt vmcnt(8)" ::: "memory")
#define WAIT0() asm volatile("s_waitcnt vmcnt(0)" ::: "memory")
#define HBAR() __builtin_amdgcn_s_barrier()

// ---------------- merged conversion kernel ----------------
__global__ __launch_bounds__(256) void cvt_all(
    const float* __restrict__ X, short* __restrict__ Xb,
    const float* __restrict__ Wq, const float* __restrict__ Wk,
    const float* __restrict__ Wv, const float* __restrict__ Wo,
    short* __restrict__ Wqkv, short* __restrict__ Wob) {
  int i = blockIdx.x * 256 + threadIdx.x;
  const int nx = 8192 * 768 / 4;
  if (i < nx) {
    float4 v = ((const float4*)X)[i];
    short4 o; o.x = f2bf(v.x); o.y = f2bf(v.y); o.z = f2bf(v.z); o.w = f2bf(v.w);
    ((short4*)Xb)[i] = o;
    return;
  }
  i -= nx;
  const int n1 = 2304 * 768 / 4;
  if (i < n1) {
    int e = i * 4;
    int row = e / 768;
    const float* src;
    float sc = 1.0f;
    if (row < 768)       { src = Wq + e; sc = QSCALE; }
    else if (row < 1536) { src = Wk + e - 768 * 768; }
    else                 { src = Wv + e - 1536 * 768; }
    float4 v = *(const float4*)src;
    short4 o; o.x = f2bf(v.x * sc); o.y = f2bf(v.y * sc);
    o.z = f2bf(v.z * sc); o.w = f2bf(v.w * sc);
    ((short4*)Wqkv)[i] = o;
  } else {
    int j = i - n1;
    if (j >= 768 * 768 / 4) return;
    float4 v = ((const float4*)Wo)[j];
    short4 o; o.x = f2bf(v.x); o.y = f2bf(v.y); o.z = f2bf(v.z); o.w = f2bf(v.w);
    ((short4*)Wob)[j] = o;
  }
}

// ======= pipelined 128x128 GEMM core, BK=64, 2-buffer, counted vmcnt =======
#define GEMM_PIPELINE(SM, AG, BG, ACC, LANE, WR, WC)                           \
  {                                                                            \
    const int l15 = (LANE) & 15, gw = (LANE) >> 4;                             \
    const int s_ = (l15 >> 1) & 3;                                             \
    const int NT = 12; /* 768/64 */                                            \
    auto stage = [&](int t) {                                                  \
      short* ab = (SM) + ((t & 1) << 13);                                      \
      short* bb = (SM) + 16384 + ((t & 1) << 13);                              \
      int kt = t << 6;                                                         \
      gload16((AG) + kt, ab + ldst);                                           \
      gload16((AG) + kt + 32 * 768, ab + ldst + 2048);                         \
      gload16((AG) + kt + 64 * 768, ab + ldst + 4096);                         \
      gload16((AG) + kt + 96 * 768, ab + ldst + 6144);                         \
      gload16((BG) + kt, bb + ldst);                                           \
      gload16((BG) + kt + 32 * 768, bb + ldst + 2048);                         \
      gload16((BG) + kt + 64 * 768, bb + ldst + 4096);                         \
      gload16((BG) + kt + 96 * 768, bb + ldst + 6144);                         \
    };                                                                         \
    auto compute = [&](int t) {                                                \
      const short* ab = (SM) + ((t & 1) << 13);                                \
      const short* bb = (SM) + 16384 + ((t & 1) << 13);                        \
      _Pragma("unroll") for (int kk = 0; kk < 2; ++kk) {                       \
        const int fc = (((kk << 2) + (gw ^ s_)) << 3);                         \
        bf16x8 af[4], bf[4];                                                   \
        _Pragma("unroll") for (int mi = 0; mi < 4; ++mi)                       \
            af[mi] = *(const bf16x8*)(ab + ((WR) + mi * 16 + l15) * 64 + fc);  \
        _Pragma("unroll") for (int ni = 0; ni < 4; ++ni)                       \
            bf[ni] = *(const bf16x8*)(bb + ((WC) + ni * 16 + l15) * 64 + fc);  \
        __builtin_amdgcn_s_setprio(1);                                         \
        _Pragma("unroll") for (int mi = 0; mi < 4; ++mi)                       \
            _Pragma("unroll") for (int ni = 0; ni < 4; ++ni)                   \
                ACC[mi][ni] = mfma16(af[mi], bf[ni], ACC[mi][ni]);             \
        __builtin_amdgcn_s_setprio(0);                                         \
      }                                                                        \
    };                                                                         \
    stage(0); stage(1);                                                        \
    SBAR();                                                                    \
    _Pragma("unroll 1") for (int i = 0; i < NT; ++i) {                         \
      SBAR();                                                                  \
      if (i < NT - 1) { WAIT8(); } else { WAIT0(); }                           \
      HBAR(); SBAR();                                                          \
      compute(i);                                                              \
      SBAR(); HBAR();                                                          \
      if (i + 2 < NT) stage(i + 2);                                            \
    }                                                                          \
  }

// ---------------- QKV projection GEMM ----------------
__global__ __launch_bounds__(256) void gemm_qkv(
    const short* __restrict__ Xb, const short* __restrict__ Wqkv,
    const float* __restrict__ bq, const float* __restrict__ bk,
    const float* __restrict__ bv,
    short* __restrict__ qO, short* __restrict__ kO, short* __restrict__ vT) {
  __shared__ __align__(16) short sm[32768];
  const int tid = threadIdx.x, lane = tid & 63, wid = tid >> 6;
  const int xcd = blockIdx.x & 7, kk = blockIdx.x >> 3;  // kk in [0,144)
  const int m0 = (xcd * 8 + (kk & 7)) * 128;
  const int n0 = (kk >> 3) * 128;
  const int wr = (wid >> 1) * 64, wc = (wid & 1) * 64;
  const int srow = tid >> 3;
  const int scol = (((tid & 7) ^ ((tid >> 4) & 3)) << 3);
  const short* Ag = Xb + (m0 + srow) * 768 + scol;
  const short* Bg = Wqkv + (n0 + srow) * 768 + scol;
  const int ldst = tid * 8;

  const int src = n0 / 768;  // 0=q 1=k 2=v
  const int nloc = n0 % 768;
  float bias[4];
#pragma unroll
  for (int ni = 0; ni < 4; ++ni) {
    int c = nloc + wc + ni * 16 + (lane & 15);
    bias[ni] = (src == 0) ? bq[c] * QSCALE : (src == 1) ? bk[c] : bv[c];
  }
  WAIT0(); SBAR();

  f32x4 acc[4][4] = {};
  GEMM_PIPELINE(sm, Ag, Bg, acc, lane, wr, wc);

  const int bb = m0 >> 12;
  const int s0 = m0 & (SEQ - 1);
  __syncthreads();
  if (src < 2) {
#pragma unroll
    for (int mi = 0; mi < 4; ++mi)
#pragma unroll
      for (int ni = 0; ni < 4; ++ni) {
        int row = wr + mi * 16 + ((lane >> 4) << 2);
        int col = wc + ni * 16 + (lane & 15);
#pragma unroll
        for (int r = 0; r < 4; ++r)
          sm[(row + r) * 132 + col] = f2bf(acc[mi][ni][r] + bias[ni]);
      }
    __syncthreads();
    short* dst = (src == 0) ? qO : kO;
    for (int u = tid; u < 8192; u += 256) {
      int r = u >> 6, cp = (u & 63) << 1;
      unsigned val = *(const unsigned*)&sm[r * 132 + cp];
      int c = nloc + cp;
      int h = c >> 6, d = c & 63;
      *(unsigned*)&dst[(((bb * NH + h) * SEQ) + s0 + r) * DH + d] = val;
    }
  } else {
#pragma unroll
    for (int mi = 0; mi < 4; ++mi)
#pragma unroll
      for (int ni = 0; ni < 4; ++ni) {
        int row = wr + mi * 16 + ((lane >> 4) << 2);
        int col = wc + ni * 16 + (lane & 15);
        short4 pk;
        pk.x = f2bf(acc[mi][ni][0] + bias[ni]);
        pk.y = f2bf(acc[mi][ni][1] + bias[ni]);
        pk.z = f2bf(acc[mi][ni][2] + bias[ni]);
        pk.w = f2bf(acc[mi][ni][3] + bias[ni]);
        *(short4*)&sm[col * 132 + row] = pk;
      }
    __syncthreads();
    for (int u = tid; u < 8192; u += 256) {
      int cc = u >> 6, rp = (u & 63) << 1;
      unsigned val = *(const unsigned*)&sm[cc * 132 + rp];
      int c = nloc + cc;
      int h = c >> 6, d = c & 63;
      *(unsigned*)&vT[(((bb * NH + h) * DH) + d) * SEQ + s0 + rp] = val;
    }
  }
}

// ---------------- sliding-window attention ----------------
// R17 structure + defer-max (THR=8), deferred l-reduce, perm P-pack.
__global__ __launch_bounds__(512, 4) void attn(
    const short* __restrict__ qI, const short* __restrict__ kI,
    const short* __restrict__ vT, const float* __restrict__ amask,
    short* __restrict__ ctx) {
  __shared__ __align__(16) short Ks[128 * 64];
  __shared__ __align__(16) short Vs[64 * 128];
  __shared__ __align__(16) short Ps[8][16 * 132];
  __shared__ __align__(16) float BiasL[768];
  const int tid = threadIdx.x, lane = tid & 63, wid = tid >> 6;
  const int vb_id = (blockIdx.x & 7) * 96 + (blockIdx.x >> 3);
  const int strip = vb_id & 31;
  const int hh = (vb_id >> 5) % 12;
  const int bb = vb_id / 384;
  const int s0 = strip * 128;
  const int n = s0 >> 8;
  const int i0 = s0 & 255;
  const int base = (n - 1) * 256;
  const int bh = bb * NH + hh;
  const int m = lane & 15, hq = lane >> 4;
  const int swz = m & 7;
  const int iw = i0 + (wid << 4);

  const short* qbase = qI + ((size_t)(bh * SEQ) + s0 + (wid << 4)) * DH;
  const bf16x8 aq0 = *(const bf16x8*)(qbase + m * DH + (hq << 3));
  const bf16x8 aq1 = *(const bf16x8*)(qbase + m * DH + 32 + (hq << 3));

  const int kb_s0 = m * 64 + ((hq ^ swz) << 3);
  const int kb_s1 = m * 64 + (((hq + 4) ^ swz) << 3);
  const int vk0 = m * 128 + ((hq ^ swz) << 3);
  const int vk1 = m * 128 + (((hq + 4) ^ swz) << 3);
  const int vk2 = m * 128 + (((hq + 8) ^ swz) << 3);
  const int vk3 = m * 128 + (((hq + 12) ^ swz) << 3);
  short* Pw = Ps[wid];
  const int pwr = m * 132;

  const int e0 = tid * 8, e1 = tid * 8 + 4096;
  const int kj0 = e0 >> 6, kj1 = e1 >> 6;
  const int ksrc0 = kj0 * DH + ((((e0 >> 3) & 7) ^ (kj0 & 7)) << 3);
  const int ksrc1 = kj1 * DH + ((((e1 >> 3) & 7) ^ (kj1 & 7)) << 3);
  const int vd0 = e0 >> 7, vd1 = e1 >> 7;
  const int vsrc0 = vd0 * SEQ + ((((e0 >> 3) & 15) ^ (vd0 & 7)) << 3);
  const int vsrc1 = vd1 * SEQ + ((((e1 >> 3) & 15) ^ (vd1 & 7)) << 3);

  const short* kg0 = kI + (size_t)bh * SEQ * DH;
  const short* vg0 = vT + (size_t)bh * DH * SEQ;

  // stage amask bias window once, pre-multiplied by -log2e
  if (tid < 192) {
    int idx = base + tid * 4;
    idx = idx < 0 ? 0 : (idx > SEQ - 4 ? SEQ - 4 : idx);
    float4 bv = *(const float4*)(amask + bb * SEQ + idx);
    bv.x *= -LOG2E; bv.y *= -LOG2E; bv.z *= -LOG2E; bv.w *= -LOG2E;
    *(float4*)&BiasL[tid * 4] = bv;
  }

  f32x4 acc[4] = {};
  float mrow = -1e30f, lrow = 0.f;  // lrow = per-lane partial

#pragma unroll 1
  for (int c = 0; c < 6; ++c) {
    const int j0 = c << 7;
    const int kpos0 = base + j0;
    if (kpos0 < 0 || kpos0 >= SEQ) continue;
    if (j0 + 127 < i0 || j0 > i0 + 639) continue;

    __syncthreads();
    {
      const short* kb = kg0 + (size_t)kpos0 * DH;
      gload16(kb + ksrc0, (short*)Ks + e0);
      gload16(kb + ksrc1, (short*)Ks + e1);
      const short* vbp = vg0 + kpos0;
      gload16(vbp + vsrc0, (short*)Vs + e0);
      gload16(vbp + vsrc1, (short*)Vs + e1);
    }
    __syncthreads();

    f32x4 sc[8];
    __builtin_amdgcn_s_setprio(1);
#pragma unroll
    for (int jt = 0; jt < 8; ++jt) {
      bf16x8 k0 = *(const bf16x8*)(Ks + jt * 1024 + kb_s0);
      bf16x8 k1 = *(const bf16x8*)(Ks + jt * 1024 + kb_s1);
      f32x4 z = {};
      z = mfma16(k0, aq0, z);
      z = mfma16(k1, aq1, z);
      sc[jt] = z;
    }
    __builtin_amdgcn_s_setprio(0);

    // bias (LDS) + (edge-only) band mask + per-lane max
    const float* mp = BiasL + j0 + (hq << 2);
    float mn_l = -3e38f;
    const bool interior = (j0 >= iw + 15) && (j0 <= iw + 385);
    if (interior) {
#pragma unroll
      for (int jt = 0; jt < 8; ++jt) {
        float4 b4 = *(const float4*)(mp + jt * 16);
#pragma unroll
        for (int r = 0; r < 4; ++r) {
          float s = sc[jt][r] + (&b4.x)[r];
          sc[jt][r] = s;
          mn_l = fmaxf(mn_l, s);
        }
      }
    } else {
      const int iq = iw + m;
#pragma unroll
      for (int jt = 0; jt < 8; ++jt) {
        float4 b4 = *(const float4*)(mp + jt * 16);
        const int jb = j0 + jt * 16 + (hq << 2);
#pragma unroll
        for (int r = 0; r < 4; ++r) {
          int j = jb + r;
          float s = sc[jt][r] + (&b4.x)[r];
          s = (j >= iq && j <= iq + 512) ? s : NEGV;
          sc[jt][r] = s;
          mn_l = fmaxf(mn_l, s);
        }
      }
    }

    // T13 defer-max: full reduce + rescale only when bound exceeded
    if (__any(mn_l > mrow + 8.0f)) {
      float mn = fmaxf(mrow, mn_l);
      mn = fmaxf(mn, __shfl_xor(mn, 16));
      mn = fmaxf(mn, __shfl_xor(mn, 32));
      const float scl = exp2f(mrow - mn);
      mrow = mn;
      lrow *= scl;  // own-lane q=m partial
      const float s0r = __shfl(scl, (hq << 2) + 0);
      const float s1r = __shfl(scl, (hq << 2) + 1);
      const float s2r = __shfl(scl, (hq << 2) + 2);
      const float s3r = __shfl(scl, (hq << 2) + 3);
#pragma unroll
      for (int nt = 0; nt < 4; ++nt) {
        acc[nt][0] *= s0r; acc[nt][1] *= s1r;
        acc[nt][2] *= s2r; acc[nt][3] *= s3r;
      }
    }

    float l0 = 0.f;
#pragma unroll
    for (int jt = 0; jt < 8; ++jt) {
      float p0 = exp2f(sc[jt][0] - mrow);
      float p1 = exp2f(sc[jt][1] - mrow);
      float p2 = exp2f(sc[jt][2] - mrow);
      float p3 = exp2f(sc[jt][3] - mrow);
      l0 += (p0 + p1) + (p2 + p3);
      uint2 u;
      u.x = pack2bf_rnd(p0, p1);
      u.y = pack2bf_rnd(p2, p3);
      *(uint2*)(Pw + pwr + jt * 16 + (hq << 2)) = u;
    }
    lrow += l0;

    asm volatile("s_waitcnt lgkmcnt(0)" ::: "memory");
    __builtin_amdgcn_sched_barrier(0);

    __builtin_amdgcn_s_setprio(1);
#pragma unroll
    for (int ks = 0; ks < 4; ++ks) {
      bf16x8 pa = *(const bf16x8*)(Pw + pwr + ks * 32 + (hq << 3));
      const int vkk = (ks == 0) ? vk0 : (ks == 1) ? vk1 : (ks == 2) ? vk2 : vk3;
#pragma unroll
      for (int nt = 0; nt < 4; ++nt) {
        bf16x8 vv = *(const bf16x8*)(Vs + nt * 2048 + vkk);
        acc[nt] = mfma16(pa, vv, acc[nt]);
      }
    }
    __builtin_amdgcn_s_setprio(0);
  }

  // epilogue: deferred l-reduce, normalize, restage, coalesced stores
  lrow += __shfl_xor(lrow, 16);
  lrow += __shfl_xor(lrow, 32);
  const float inv = 1.0f / lrow;
  const float i0r = __shfl(inv, (hq << 2) + 0);
  const float i1r = __shfl(inv, (hq << 2) + 1);
  const float i2r = __shfl(inv, (hq << 2) + 2);
  const float i3r = __shfl(inv, (hq << 2) + 3);
#pragma unroll
  for (int nt = 0; nt < 4; ++nt) {
    Pw[((hq << 2) + 0) * 72 + nt * 16 + m] = f2bf(acc[nt][0] * i0r);
    Pw[((hq << 2) + 1) * 72 + nt * 16 + m] = f2bf(acc[nt][1] * i1r);
    Pw[((hq << 2) + 2) * 72 + nt * 16 + m] = f2bf(acc[nt][2] * i2r);
    Pw[((hq << 2) + 3) * 72 + nt * 16 + m] = f2bf(acc[nt][3] * i3r);
  }
  asm volatile("s_waitcnt lgkmcnt(0)" ::: "memory");
  __builtin_amdgcn_sched_barrier(0);
#pragma unroll
  for (int it = 0; it < 2; ++it) {
    int row = it * 8 + (lane >> 3);
    bf16x8 val = *(const bf16x8*)(Pw + row * 72 + ((lane & 7) << 3));
    *(bf16x8*)(ctx + ((size_t)(bb * SEQ) + s0 + (wid << 4) + row) * DM +
               hh * DH + ((lane & 7) << 3)) = val;
  }
}

// ---------------- output projection GEMM (BK=64 pipelined) ----------------
__global__ __launch_bounds__(256) void gemm_out(
    const short* __restrict__ Cb, const short* __restrict__ Wob,
    const float* __restrict__ bo, float* __restrict__ out) {
  __shared__ __align__(16) short sm[32768];
  const int tid = threadIdx.x, lane = tid & 63, wid = tid >> 6;
  const int xcd = blockIdx.x & 7, kk = blockIdx.x >> 3;  // kk in [0,48)
  const int m0 = (xcd * 8 + (kk & 7)) * 128;
  const int n0 = (kk >> 3) * 128;
  const int wr = (wid >> 1) * 64, wc = (wid & 1) * 64;
  const int srow = tid >> 3;
  const int scol = (((tid & 7) ^ ((tid >> 4) & 3)) << 3);
  const short* Ag = Cb + (m0 + srow) * 768 + scol;
  const short* Bg = Wob + (n0 + srow) * 768 + scol;
  const int ldst = tid * 8;

  float bias[4];
#pragma unroll
  for (int ni = 0; ni < 4; ++ni)
    bias[ni] = bo[n0 + wc + ni * 16 + (lane & 15)];
  WAIT0(); SBAR();

  f32x4 acc[4][4] = {};
  GEMM_PIPELINE(sm, Ag, Bg, acc, lane, wr, wc);

#pragma unroll
  for (int mi = 0; mi < 4; ++mi)
#pragma unroll
    for (int ni = 0; ni < 4; ++ni) {
      int row = m0 + wr + mi * 16 + ((lane >> 4) << 2);
      int col = n0 + wc + ni * 16 + (lane & 15);
#pragma unroll
      for (int r = 0; r < 4; ++r)
        out[(row + r) * DM + col] = acc[mi][ni][r] + bias[ni];
    }
}

// ---------------- launcher ----------------
extern "C" void kernel_launch(void* const* d_in, const int* in_sizes, int n_in,
                              void* d_out, int out_size, void* d_ws, size_t ws_size,
                              hipStream_t stream) {
  (void)in_sizes; (void)n_in; (void)out_size; (void)ws_size;
  const float* hs    = (const float*)d_in[0];
  const float* amask = (const float*)d_in[1];
  const float* Wq = (const float*)d_in[2];
  const float* bq = (const float*)d_in[3];
  const float* Wk = (const float*)d_in[4];
  const float* bk = (const float*)d_in[5];
  const float* Wv = (const float*)d_in[6];
  const float* bv = (const float*)d_in[7];
  const float* Wo = (const float*)d_in[8];
  const float* bo = (const float*)d_in[9];
  float* out = (float*)d_out;
  char* ws = (char*)d_ws;
  short* Xb   = (short*)(ws);
  short* Wqkv = (short*)(ws + 12582912);
  short* Wob  = (short*)(ws + 16121856);
  short* qB   = (short*)(ws + 17301504);
  short* kB   = (short*)(ws + 29884416);
  short* vTB  = (short*)(ws + 42467328);
  short* ctx  = Xb;  // Xb dead after gemm_qkv

  cvt_all<<<dim3(8448), dim3(256), 0, stream>>>(hs, Xb, Wq, Wk, Wv, Wo, Wqkv, Wob);
  gemm_qkv<<<dim3(1152), dim3(256), 0, stream>>>(Xb, Wqkv, bq, bk, bv, qB, kB, vTB);
  attn<<<dim3(768), dim3(512), 0, stream>>>(qB, kB, vTB, amask, ctx);
  gemm_out<<<dim3(384), dim3(256), 0, stream>>>(ctx, Wob, bo, out);
}

// Round 21
// 121.775 us; speedup vs baseline: 1.1206x; 1.0143x over previous
//
#include <hip/hip_runtime.h>
#include <hip/hip_bf16.h>
#include <stdint.h>

#define NH 12
#define DH 64
#define SEQ 4096
#define DM 768
#define NEGV -1e9f
#define LOG2E 1.4426950408889634f
#define QSCALE 0.1803368801111601f  // 0.125 * log2(e)

using bf16x8 = __attribute__((ext_vector_type(8))) short;
using f32x4  = __attribute__((ext_vector_type(4))) float;

static __device__ __forceinline__ short f2bf(float f) {
  unsigned u = __builtin_bit_cast(unsigned, f);
  u += 0x7fffu + ((u >> 16) & 1u);
  return (short)(u >> 16);
}

// round-half-up bf16 pair pack via v_perm_b32
static __device__ __forceinline__ unsigned pack2bf_rnd(float lo, float hi) {
  unsigned a = __builtin_bit_cast(unsigned, lo) + 0x8000u;
  unsigned b = __builtin_bit_cast(unsigned, hi) + 0x8000u;
  return __builtin_amdgcn_perm(b, a, 0x07060302u);
}

static __device__ __forceinline__ void gload16(const void* g, void* l) {
  __builtin_amdgcn_global_load_lds(
      (const __attribute__((address_space(1))) unsigned*)g,
      (__attribute__((address_space(3))) unsigned*)l, 16, 0, 0);
}

static __device__ __forceinline__ f32x4 mfma16(bf16x8 a, bf16x8 b, f32x4 c) {
  return __builtin_amdgcn_mfma_f32_16x16x32_bf16(a, b, c, 0, 0, 0);
}

#define SBAR() __builtin_amdgcn_sched_barrier(0)
#define WAIT8() asm volatile("s_waitcnt vmcnt(8)" ::: "memory")
#define WAIT4() asm volatile("s_waitcnt vmcnt(4)" ::: "memory")
#define WAIT0() asm volatile("s_waitcnt vmcnt(0)" ::: "memory")
#define HBAR() __builtin_amdgcn_s_barrier()

// ---------------- merged conversion kernel ----------------
__global__ __launch_bounds__(256) void cvt_all(
    const float* __restrict__ X, short* __restrict__ Xb,
    const float* __restrict__ Wq, const float* __restrict__ Wk,
    const float* __restrict__ Wv, const float* __restrict__ Wo,
    short* __restrict__ Wqkv, short* __restrict__ Wob) {
  int i = blockIdx.x * 256 + threadIdx.x;
  const int nx = 8192 * 768 / 4;
  if (i < nx) {
    float4 v = ((const float4*)X)[i];
    short4 o; o.x = f2bf(v.x); o.y = f2bf(v.y); o.z = f2bf(v.z); o.w = f2bf(v.w);
    ((short4*)Xb)[i] = o;
    return;
  }
  i -= nx;
  const int n1 = 2304 * 768 / 4;
  if (i < n1) {
    int e = i * 4;
    int row = e / 768;
    const float* src;
    float sc = 1.0f;
    if (row < 768)       { src = Wq + e; sc = QSCALE; }
    else if (row < 1536) { src = Wk + e - 768 * 768; }
    else                 { src = Wv + e - 1536 * 768; }
    float4 v = *(const float4*)src;
    short4 o; o.x = f2bf(v.x * sc); o.y = f2bf(v.y * sc);
    o.z = f2bf(v.z * sc); o.w = f2bf(v.w * sc);
    ((short4*)Wqkv)[i] = o;
  } else {
    int j = i - n1;
    if (j >= 768 * 768 / 4) return;
    float4 v = ((const float4*)Wo)[j];
    short4 o; o.x = f2bf(v.x); o.y = f2bf(v.y); o.z = f2bf(v.z); o.w = f2bf(v.w);
    ((short4*)Wob)[j] = o;
  }
}

// ======= 128x128 BK=64 2-buffer pipeline, 256 threads (R16) — gemm_out =====
#define GEMM_PIPELINE(SM, AG, BG, ACC, LANE, WR, WC)                           \
  {                                                                            \
    const int l15 = (LANE) & 15, gw = (LANE) >> 4;                             \
    const int s_ = (l15 >> 1) & 3;                                             \
    const int NT = 12; /* 768/64 */                                            \
    auto stage = [&](int t) {                                                  \
      short* ab = (SM) + ((t & 1) << 13);                                      \
      short* bb = (SM) + 16384 + ((t & 1) << 13);                              \
      int kt = t << 6;                                                         \
      gload16((AG) + kt, ab + ldst);                                           \
      gload16((AG) + kt + 32 * 768, ab + ldst + 2048);                         \
      gload16((AG) + kt + 64 * 768, ab + ldst + 4096);                         \
      gload16((AG) + kt + 96 * 768, ab + ldst + 6144);                         \
      gload16((BG) + kt, bb + ldst);                                           \
      gload16((BG) + kt + 32 * 768, bb + ldst + 2048);                         \
      gload16((BG) + kt + 64 * 768, bb + ldst + 4096);                         \
      gload16((BG) + kt + 96 * 768, bb + ldst + 6144);                         \
    };                                                                         \
    auto compute = [&](int t) {                                                \
      const short* ab = (SM) + ((t & 1) << 13);                                \
      const short* bb = (SM) + 16384 + ((t & 1) << 13);                        \
      _Pragma("unroll") for (int kk = 0; kk < 2; ++kk) {                       \
        const int fc = (((kk << 2) + (gw ^ s_)) << 3);                         \
        bf16x8 af[4], bf[4];                                                   \
        _Pragma("unroll") for (int mi = 0; mi < 4; ++mi)                       \
            af[mi] = *(const bf16x8*)(ab + ((WR) + mi * 16 + l15) * 64 + fc);  \
        _Pragma("unroll") for (int ni = 0; ni < 4; ++ni)                       \
            bf[ni] = *(const bf16x8*)(bb + ((WC) + ni * 16 + l15) * 64 + fc);  \
        __builtin_amdgcn_s_setprio(1);                                         \
        _Pragma("unroll") for (int mi = 0; mi < 4; ++mi)                       \
            _Pragma("unroll") for (int ni = 0; ni < 4; ++ni)                   \
                ACC[mi][ni] = mfma16(af[mi], bf[ni], ACC[mi][ni]);             \
        __builtin_amdgcn_s_setprio(0);                                         \
      }                                                                        \
    };                                                                         \
    stage(0); stage(1);                                                        \
    SBAR();                                                                    \
    _Pragma("unroll 1") for (int i = 0; i < NT; ++i) {                         \
      SBAR();                                                                  \
      if (i < NT - 1) { WAIT8(); } else { WAIT0(); }                           \
      HBAR(); SBAR();                                                          \
      compute(i);                                                              \
      SBAR(); HBAR();                                                          \
      if (i + 2 < NT) stage(i + 2);                                            \
    }                                                                          \
  }

// ---------------- QKV projection GEMM: 128x128, BK=64, 512 threads --------
// 8 waves as 4m x 2n (32x64 each, acc[2][4]); stage = 4 loads/thread,
// counted vmcnt(4). LDS 64KB -> 2 blocks/CU = 16 waves/CU.
__global__ __launch_bounds__(512) void gemm_qkv(
    const short* __restrict__ Xb, const short* __restrict__ Wqkv,
    const float* __restrict__ bq, const float* __restrict__ bk,
    const float* __restrict__ bv,
    short* __restrict__ qO, short* __restrict__ kO, short* __restrict__ vT) {
  __shared__ __align__(16) short sm[32768];
  const int tid = threadIdx.x, lane = tid & 63, wid = tid >> 6;
  const int xcd = blockIdx.x & 7, kk = blockIdx.x >> 3;  // kk in [0,144)
  const int m0 = (xcd * 8 + (kk & 7)) * 128;
  const int n0 = (kk >> 3) * 128;
  const int wr = (wid >> 1) * 32, wc = (wid & 1) * 64;
  const int l15 = lane & 15, gw = lane >> 4;
  const int s_ = (l15 >> 1) & 3;
  const int ldst = tid * 8;

  // staging offsets: 2 passes of 512x8 shorts per operand, swizzled source
  int off0, off1;
  {
    int e = ldst;            int row = e >> 6;
    off0 = row * 768 + (((((e >> 3) & 7) ^ ((row >> 1) & 3))) << 3);
    e = 4096 + ldst;         row = e >> 6;
    off1 = row * 768 + (((((e >> 3) & 7) ^ ((row >> 1) & 3))) << 3);
  }
  const short* Ag = Xb + (size_t)m0 * 768;
  const short* Bg = Wqkv + (size_t)n0 * 768;

  const int src = n0 / 768;  // 0=q 1=k 2=v
  const int nloc = n0 % 768;
  float bias[4];
#pragma unroll
  for (int ni = 0; ni < 4; ++ni) {
    int c = nloc + wc + ni * 16 + l15;
    bias[ni] = (src == 0) ? bq[c] * QSCALE : (src == 1) ? bk[c] : bv[c];
  }
  WAIT0(); SBAR();

  auto stage = [&](int t) {
    short* ab = sm + ((t & 1) << 13);
    short* bb = sm + 16384 + ((t & 1) << 13);
    int kt = t << 6;
    gload16(Ag + off0 + kt, ab + ldst);
    gload16(Ag + off1 + kt, ab + 4096 + ldst);
    gload16(Bg + off0 + kt, bb + ldst);
    gload16(Bg + off1 + kt, bb + 4096 + ldst);
  };
  f32x4 acc[2][4] = {};
  auto compute = [&](int t) {
    const short* ab = sm + ((t & 1) << 13);
    const short* bb = sm + 16384 + ((t & 1) << 13);
#pragma unroll
    for (int kk2 = 0; kk2 < 2; ++kk2) {
      const int fc = (((kk2 << 2) + (gw ^ s_)) << 3);
      bf16x8 af[2], bf[4];
#pragma unroll
      for (int mi = 0; mi < 2; ++mi)
        af[mi] = *(const bf16x8*)(ab + (wr + mi * 16 + l15) * 64 + fc);
#pragma unroll
      for (int ni = 0; ni < 4; ++ni)
        bf[ni] = *(const bf16x8*)(bb + (wc + ni * 16 + l15) * 64 + fc);
      __builtin_amdgcn_s_setprio(1);
#pragma unroll
      for (int mi = 0; mi < 2; ++mi)
#pragma unroll
        for (int ni = 0; ni < 4; ++ni)
          acc[mi][ni] = mfma16(af[mi], bf[ni], acc[mi][ni]);
      __builtin_amdgcn_s_setprio(0);
    }
  };

  stage(0); stage(1);
  SBAR();
#pragma unroll 1
  for (int i = 0; i < 12; ++i) {
    SBAR();
    if (i < 11) { WAIT4(); } else { WAIT0(); }
    HBAR(); SBAR();
    compute(i);
    SBAR(); HBAR();
    if (i + 2 < 12) stage(i + 2);
  }

  const int bb_ = m0 >> 12;
  const int s0 = m0 & (SEQ - 1);
  __syncthreads();
  if (src < 2) {
#pragma unroll
    for (int mi = 0; mi < 2; ++mi)
#pragma unroll
      for (int ni = 0; ni < 4; ++ni) {
        int row = wr + mi * 16 + ((lane >> 4) << 2);
        int col = wc + ni * 16 + l15;
#pragma unroll
        for (int r = 0; r < 4; ++r)
          sm[(row + r) * 132 + col] = f2bf(acc[mi][ni][r] + bias[ni]);
      }
    __syncthreads();
    short* dst = (src == 0) ? qO : kO;
    for (int u = tid; u < 8192; u += 512) {
      int r = u >> 6, cp = (u & 63) << 1;
      unsigned val = *(const unsigned*)&sm[r * 132 + cp];
      int c = nloc + cp;
      int h = c >> 6, d = c & 63;
      *(unsigned*)&dst[(((bb_ * NH + h) * SEQ) + s0 + r) * DH + d] = val;
    }
  } else {
#pragma unroll
    for (int mi = 0; mi < 2; ++mi)
#pragma unroll
      for (int ni = 0; ni < 4; ++ni) {
        int row = wr + mi * 16 + ((lane >> 4) << 2);
        int col = wc + ni * 16 + l15;
        short4 pk;
        pk.x = f2bf(acc[mi][ni][0] + bias[ni]);
        pk.y = f2bf(acc[mi][ni][1] + bias[ni]);
        pk.z = f2bf(acc[mi][ni][2] + bias[ni]);
        pk.w = f2bf(acc[mi][ni][3] + bias[ni]);
        *(short4*)&sm[col * 132 + row] = pk;
      }
    __syncthreads();
    for (int u = tid; u < 8192; u += 512) {
      int cc = u >> 6, rp = (u & 63) << 1;
      unsigned val = *(const unsigned*)&sm[cc * 132 + rp];
      int c = nloc + cc;
      int h = c >> 6, d = c & 63;
      *(unsigned*)&vT[(((bb_ * NH + h) * DH) + d) * SEQ + s0 + rp] = val;
    }
  }
}

// ---------------- sliding-window attention (R18/R20-exact) ----------------
__global__ __launch_bounds__(512, 4) void attn(
    const short* __restrict__ qI, const short* __restrict__ kI,
    const short* __restrict__ vT, const float* __restrict__ amask,
    short* __restrict__ ctx) {
  __shared__ __align__(16) short Ks[128 * 64];
  __shared__ __align__(16) short Vs[64 * 128];
  __shared__ __align__(16) short Ps[8][16 * 132];
  __shared__ __align__(16) float BiasL[768];
  const int tid = threadIdx.x, lane = tid & 63, wid = tid >> 6;
  const int vb_id = (blockIdx.x & 7) * 96 + (blockIdx.x >> 3);
  const int strip = vb_id & 31;
  const int hh = (vb_id >> 5) % 12;
  const int bb = vb_id / 384;
  const int s0 = strip * 128;
  const int n = s0 >> 8;
  const int i0 = s0 & 255;
  const int base = (n - 1) * 256;
  const int bh = bb * NH + hh;
  const int m = lane & 15, hq = lane >> 4;
  const int swz = m & 7;
  const int iw = i0 + (wid << 4);

  const short* qbase = qI + ((size_t)(bh * SEQ) + s0 + (wid << 4)) * DH;
  const bf16x8 aq0 = *(const bf16x8*)(qbase + m * DH + (hq << 3));
  const bf16x8 aq1 = *(const bf16x8*)(qbase + m * DH + 32 + (hq << 3));

  const int kb_s0 = m * 64 + ((hq ^ swz) << 3);
  const int kb_s1 = m * 64 + (((hq + 4) ^ swz) << 3);
  const int vk0 = m * 128 + ((hq ^ swz) << 3);
  const int vk1 = m * 128 + (((hq + 4) ^ swz) << 3);
  const int vk2 = m * 128 + (((hq + 8) ^ swz) << 3);
  const int vk3 = m * 128 + (((hq + 12) ^ swz) << 3);
  short* Pw = Ps[wid];
  const int pwr = m * 132;

  const int e0 = tid * 8, e1 = tid * 8 + 4096;
  const int kj0 = e0 >> 6, kj1 = e1 >> 6;
  const int ksrc0 = kj0 * DH + ((((e0 >> 3) & 7) ^ (kj0 & 7)) << 3);
  const int ksrc1 = kj1 * DH + ((((e1 >> 3) & 7) ^ (kj1 & 7)) << 3);
  const int vd0 = e0 >> 7, vd1 = e1 >> 7;
  const int vsrc0 = vd0 * SEQ + ((((e0 >> 3) & 15) ^ (vd0 & 7)) << 3);
  const int vsrc1 = vd1 * SEQ + ((((e1 >> 3) & 15) ^ (vd1 & 7)) << 3);

  const short* kg0 = kI + (size_t)bh * SEQ * DH;
  const short* vg0 = vT + (size_t)bh * DH * SEQ;

  if (tid < 192) {
    int idx = base + tid * 4;
    idx = idx < 0 ? 0 : (idx > SEQ - 4 ? SEQ - 4 : idx);
    float4 bv = *(const float4*)(amask + bb * SEQ + idx);
    bv.x *= -LOG2E; bv.y *= -LOG2E; bv.z *= -LOG2E; bv.w *= -LOG2E;
    *(float4*)&BiasL[tid * 4] = bv;
  }

  f32x4 acc[4] = {};
  float mrow = -1e30f, lrow = 0.f;

#pragma unroll 1
  for (int c = 0; c < 6; ++c) {
    const int j0 = c << 7;
    const int kpos0 = base + j0;
    if (kpos0 < 0 || kpos0 >= SEQ) continue;
    if (j0 + 127 < i0 || j0 > i0 + 639) continue;

    __syncthreads();
    {
      const short* kb = kg0 + (size_t)kpos0 * DH;
      gload16(kb + ksrc0, (short*)Ks + e0);
      gload16(kb + ksrc1, (short*)Ks + e1);
      const short* vbp = vg0 + kpos0;
      gload16(vbp + vsrc0, (short*)Vs + e0);
      gload16(vbp + vsrc1, (short*)Vs + e1);
    }
    __syncthreads();

    f32x4 sc[8];
    __builtin_amdgcn_s_setprio(1);
#pragma unroll
    for (int jt = 0; jt < 8; ++jt) {
      bf16x8 k0 = *(const bf16x8*)(Ks + jt * 1024 + kb_s0);
      bf16x8 k1 = *(const bf16x8*)(Ks + jt * 1024 + kb_s1);
      f32x4 z = {};
      z = mfma16(k0, aq0, z);
      z = mfma16(k1, aq1, z);
      sc[jt] = z;
    }
    __builtin_amdgcn_s_setprio(0);

    const float* mp = BiasL + j0 + (hq << 2);
    float mn_l = -3e38f;
    const bool interior = (j0 >= iw + 15) && (j0 <= iw + 385);
    if (interior) {
#pragma unroll
      for (int jt = 0; jt < 8; ++jt) {
        float4 b4 = *(const float4*)(mp + jt * 16);
#pragma unroll
        for (int r = 0; r < 4; ++r) {
          float s = sc[jt][r] + (&b4.x)[r];
          sc[jt][r] = s;
          mn_l = fmaxf(mn_l, s);
        }
      }
    } else {
      const int iq = iw + m;
#pragma unroll
      for (int jt = 0; jt < 8; ++jt) {
        float4 b4 = *(const float4*)(mp + jt * 16);
        const int jb = j0 + jt * 16 + (hq << 2);
#pragma unroll
        for (int r = 0; r < 4; ++r) {
          int j = jb + r;
          float s = sc[jt][r] + (&b4.x)[r];
          s = (j >= iq && j <= iq + 512) ? s : NEGV;
          sc[jt][r] = s;
          mn_l = fmaxf(mn_l, s);
        }
      }
    }

    if (__any(mn_l > mrow + 8.0f)) {
      float mn = fmaxf(mrow, mn_l);
      mn = fmaxf(mn, __shfl_xor(mn, 16));
      mn = fmaxf(mn, __shfl_xor(mn, 32));
      const float scl = exp2f(mrow - mn);
      mrow = mn;
      lrow *= scl;
      const float s0r = __shfl(scl, (hq << 2) + 0);
      const float s1r = __shfl(scl, (hq << 2) + 1);
      const float s2r = __shfl(scl, (hq << 2) + 2);
      const float s3r = __shfl(scl, (hq << 2) + 3);
#pragma unroll
      for (int nt = 0; nt < 4; ++nt) {
        acc[nt][0] *= s0r; acc[nt][1] *= s1r;
        acc[nt][2] *= s2r; acc[nt][3] *= s3r;
      }
    }

    float l0 = 0.f;
#pragma unroll
    for (int jt = 0; jt < 8; ++jt) {
      float p0 = exp2f(sc[jt][0] - mrow);
      float p1 = exp2f(sc[jt][1] - mrow);
      float p2 = exp2f(sc[jt][2] - mrow);
      float p3 = exp2f(sc[jt][3] - mrow);
      l0 += (p0 + p1) + (p2 + p3);
      uint2 u;
      u.x = pack2bf_rnd(p0, p1);
      u.y = pack2bf_rnd(p2, p3);
      *(uint2*)(Pw + pwr + jt * 16 + (hq << 2)) = u;
    }
    lrow += l0;

    asm volatile("s_waitcnt lgkmcnt(0)" ::: "memory");
    __builtin_amdgcn_sched_barrier(0);

    __builtin_amdgcn_s_setprio(1);
#pragma unroll
    for (int ks = 0; ks < 4; ++ks) {
      bf16x8 pa = *(const bf16x8*)(Pw + pwr + ks * 32 + (hq << 3));
      const int vkk = (ks == 0) ? vk0 : (ks == 1) ? vk1 : (ks == 2) ? vk2 : vk3;
#pragma unroll
      for (int nt = 0; nt < 4; ++nt) {
        bf16x8 vv = *(const bf16x8*)(Vs + nt * 2048 + vkk);
        acc[nt] = mfma16(pa, vv, acc[nt]);
      }
    }
    __builtin_amdgcn_s_setprio(0);
  }

  lrow += __shfl_xor(lrow, 16);
  lrow += __shfl_xor(lrow, 32);
  const float inv = 1.0f / lrow;
  const float i0r = __shfl(inv, (hq << 2) + 0);
  const float i1r = __shfl(inv, (hq << 2) + 1);
  const float i2r = __shfl(inv, (hq << 2) + 2);
  const float i3r = __shfl(inv, (hq << 2) + 3);
#pragma unroll
  for (int nt = 0; nt < 4; ++nt) {
    Pw[((hq << 2) + 0) * 72 + nt * 16 + m] = f2bf(acc[nt][0] * i0r);
    Pw[((hq << 2) + 1) * 72 + nt * 16 + m] = f2bf(acc[nt][1] * i1r);
    Pw[((hq << 2) + 2) * 72 + nt * 16 + m] = f2bf(acc[nt][2] * i2r);
    Pw[((hq << 2) + 3) * 72 + nt * 16 + m] = f2bf(acc[nt][3] * i3r);
  }
  asm volatile("s_waitcnt lgkmcnt(0)" ::: "memory");
  __builtin_amdgcn_sched_barrier(0);
#pragma unroll
  for (int it = 0; it < 2; ++it) {
    int row = it * 8 + (lane >> 3);
    bf16x8 val = *(const bf16x8*)(Pw + row * 72 + ((lane & 7) << 3));
    *(bf16x8*)(ctx + ((size_t)(bb * SEQ) + s0 + (wid << 4) + row) * DM +
               hh * DH + ((lane & 7) << 3)) = val;
  }
}

// ---------------- output projection GEMM (BK=64 pipelined, 256 thr) -------
__global__ __launch_bounds__(256) void gemm_out(
    const short* __restrict__ Cb, const short* __restrict__ Wob,
    const float* __restrict__ bo, float* __restrict__ out) {
  __shared__ __align__(16) short sm[32768];
  const int tid = threadIdx.x, lane = tid & 63, wid = tid >> 6;
  const int xcd = blockIdx.x & 7, kk = blockIdx.x >> 3;  // kk in [0,48)
  const int m0 = (xcd * 8 + (kk & 7)) * 128;
  const int n0 = (kk >> 3) * 128;
  const int wr = (wid >> 1) * 64, wc = (wid & 1) * 64;
  const int srow = tid >> 3;
  const int scol = (((tid & 7) ^ ((tid >> 4) & 3)) << 3);
  const short* Ag = Cb + (m0 + srow) * 768 + scol;
  const short* Bg = Wob + (n0 + srow) * 768 + scol;
  const int ldst = tid * 8;

  float bias[4];
#pragma unroll
  for (int ni = 0; ni < 4; ++ni)
    bias[ni] = bo[n0 + wc + ni * 16 + (lane & 15)];
  WAIT0(); SBAR();

  f32x4 acc[4][4] = {};
  GEMM_PIPELINE(sm, Ag, Bg, acc, lane, wr, wc);

#pragma unroll
  for (int mi = 0; mi < 4; ++mi)
#pragma unroll
    for (int ni = 0; ni < 4; ++ni) {
      int row = m0 + wr + mi * 16 + ((lane >> 4) << 2);
      int col = n0 + wc + ni * 16 + (lane & 15);
#pragma unroll
      for (int r = 0; r < 4; ++r)
        out[(row + r) * DM + col] = acc[mi][ni][r] + bias[ni];
    }
}

// ---------------- launcher ----------------
extern "C" void kernel_launch(void* const* d_in, const int* in_sizes, int n_in,
                              void* d_out, int out_size, void* d_ws, size_t ws_size,
                              hipStream_t stream) {
  (void)in_sizes; (void)n_in; (void)out_size; (void)ws_size;
  const float* hs    = (const float*)d_in[0];
  const float* amask = (const float*)d_in[1];
  const float* Wq = (const float*)d_in[2];
  const float* bq = (const float*)d_in[3];
  const float* Wk = (const float*)d_in[4];
  const float* bk = (const float*)d_in[5];
  const float* Wv = (const float*)d_in[6];
  const float* bv = (const float*)d_in[7];
  const float* Wo = (const float*)d_in[8];
  const float* bo = (const float*)d_in[9];
  float* out = (float*)d_out;
  char* ws = (char*)d_ws;
  short* Xb   = (short*)(ws);
  short* Wqkv = (short*)(ws + 12582912);
  short* Wob  = (short*)(ws + 16121856);
  short* qB   = (short*)(ws + 17301504);
  short* kB   = (short*)(ws + 29884416);
  short* vTB  = (short*)(ws + 42467328);
  short* ctx  = Xb;  // Xb dead after gemm_qkv

  cvt_all<<<dim3(8448), dim3(256), 0, stream>>>(hs, Xb, Wq, Wk, Wv, Wo, Wqkv, Wob);
  gemm_qkv<<<dim3(1152), dim3(512), 0, stream>>>(Xb, Wqkv, bq, bk, bv, qB, kB, vTB);
  attn<<<dim3(768), dim3(512), 0, stream>>>(qB, kB, vTB, amask, ctx);
  gemm_out<<<dim3(384), dim3(256), 0, stream>>>(ctx, Wob, bo, out);
}

// Round 22
// 121.584 us; speedup vs baseline: 1.1223x; 1.0016x over previous
//
#include <hip/hip_runtime.h>
#include <hip/hip_bf16.h>
#include <stdint.h>

#define NH 12
#define DH 64
#define SEQ 4096
#define DM 768
#define NEGV -1e9f
#define LOG2E 1.4426950408889634f
#define QSCALE 0.1803368801111601f  // 0.125 * log2(e)

using bf16x8 = __attribute__((ext_vector_type(8))) short;
using f32x4  = __attribute__((ext_vector_type(4))) float;

static __device__ __forceinline__ short f2bf(float f) {
  unsigned u = __builtin_bit_cast(unsigned, f);
  u += 0x7fffu + ((u >> 16) & 1u);
  return (short)(u >> 16);
}

// round-half-up bf16 pair pack via v_perm_b32
static __device__ __forceinline__ unsigned pack2bf_rnd(float lo, float hi) {
  unsigned a = __builtin_bit_cast(unsigned, lo) + 0x8000u;
  unsigned b = __builtin_bit_cast(unsigned, hi) + 0x8000u;
  return __builtin_amdgcn_perm(b, a, 0x07060302u);
}

static __device__ __forceinline__ void gload16(const void* g, void* l) {
  __builtin_amdgcn_global_load_lds(
      (const __attribute__((address_space(1))) unsigned*)g,
      (__attribute__((address_space(3))) unsigned*)l, 16, 0, 0);
}

static __device__ __forceinline__ f32x4 mfma16(bf16x8 a, bf16x8 b, f32x4 c) {
  return __builtin_amdgcn_mfma_f32_16x16x32_bf16(a, b, c, 0, 0, 0);
}

#define SBAR() __builtin_amdgcn_sched_barrier(0)
#define WAIT4() asm volatile("s_waitcnt vmcnt(4)" ::: "memory")
#define WAIT0() asm volatile("s_waitcnt vmcnt(0)" ::: "memory")
#define HBAR() __builtin_amdgcn_s_barrier()

// ---------------- merged conversion kernel ----------------
__global__ __launch_bounds__(256) void cvt_all(
    const float* __restrict__ X, short* __restrict__ Xb,
    const float* __restrict__ Wq, const float* __restrict__ Wk,
    const float* __restrict__ Wv, const float* __restrict__ Wo,
    short* __restrict__ Wqkv, short* __restrict__ Wob) {
  int i = blockIdx.x * 256 + threadIdx.x;
  const int nx = 8192 * 768 / 4;
  if (i < nx) {
    float4 v = ((const float4*)X)[i];
    short4 o; o.x = f2bf(v.x); o.y = f2bf(v.y); o.z = f2bf(v.z); o.w = f2bf(v.w);
    ((short4*)Xb)[i] = o;
    return;
  }
  i -= nx;
  const int n1 = 2304 * 768 / 4;
  if (i < n1) {
    int e = i * 4;
    int row = e / 768;
    const float* src;
    float sc = 1.0f;
    if (row < 768)       { src = Wq + e; sc = QSCALE; }
    else if (row < 1536) { src = Wk + e - 768 * 768; }
    else                 { src = Wv + e - 1536 * 768; }
    float4 v = *(const float4*)src;
    short4 o; o.x = f2bf(v.x * sc); o.y = f2bf(v.y * sc);
    o.z = f2bf(v.z * sc); o.w = f2bf(v.w * sc);
    ((short4*)Wqkv)[i] = o;
  } else {
    int j = i - n1;
    if (j >= 768 * 768 / 4) return;
    float4 v = ((const float4*)Wo)[j];
    short4 o; o.x = f2bf(v.x); o.y = f2bf(v.y); o.z = f2bf(v.z); o.w = f2bf(v.w);
    ((short4*)Wob)[j] = o;
  }
}

// ======= 128x128 BK=64 2-buffer pipeline, 512 threads (R21 core) =======
// 8 waves as 4m x 2n (32x64 each, acc[2][4]); stage = 4 loads/thread,
// counted vmcnt(4). LDS 64KB -> 2 blocks/CU = 16 waves/CU.
#define GEMM_CORE_512(AG, BG, ACC)                                             \
  {                                                                            \
    auto stage = [&](int t) {                                                  \
      short* ab = sm + ((t & 1) << 13);                                        \
      short* bb = sm + 16384 + ((t & 1) << 13);                                \
      int kt = t << 6;                                                         \
      gload16((AG) + off0 + kt, ab + ldst);                                    \
      gload16((AG) + off1 + kt, ab + 4096 + ldst);                             \
      gload16((BG) + off0 + kt, bb + ldst);                                    \
      gload16((BG) + off1 + kt, bb + 4096 + ldst);                             \
    };                                                                         \
    auto compute = [&](int t) {                                                \
      const short* ab = sm + ((t & 1) << 13);                                  \
      const short* bb = sm + 16384 + ((t & 1) << 13);                          \
      _Pragma("unroll") for (int kk2 = 0; kk2 < 2; ++kk2) {                    \
        const int fc = (((kk2 << 2) + (gw ^ s_)) << 3);                        \
        bf16x8 af[2], bf[4];                                                   \
        _Pragma("unroll") for (int mi = 0; mi < 2; ++mi)                       \
            af[mi] = *(const bf16x8*)(ab + (wr + mi * 16 + l15) * 64 + fc);    \
        _Pragma("unroll") for (int ni = 0; ni < 4; ++ni)                       \
            bf[ni] = *(const bf16x8*)(bb + (wc + ni * 16 + l15) * 64 + fc);    \
        __builtin_amdgcn_s_setprio(1);                                         \
        _Pragma("unroll") for (int mi = 0; mi < 2; ++mi)                       \
            _Pragma("unroll") for (int ni = 0; ni < 4; ++ni)                   \
                ACC[mi][ni] = mfma16(af[mi], bf[ni], ACC[mi][ni]);             \
        __builtin_amdgcn_s_setprio(0);                                         \
      }                                                                        \
    };                                                                         \
    stage(0); stage(1);                                                        \
    SBAR();                                                                    \
    _Pragma("unroll 1") for (int i = 0; i < 12; ++i) {                         \
      SBAR();                                                                  \
      if (i < 11) { WAIT4(); } else { WAIT0(); }                               \
      HBAR(); SBAR();                                                          \
      compute(i);                                                              \
      SBAR(); HBAR();                                                          \
      if (i + 2 < 12) stage(i + 2);                                            \
    }                                                                          \
  }

// ---------------- QKV projection GEMM (R21) ----------------
__global__ __launch_bounds__(512) void gemm_qkv(
    const short* __restrict__ Xb, const short* __restrict__ Wqkv,
    const float* __restrict__ bq, const float* __restrict__ bk,
    const float* __restrict__ bv,
    short* __restrict__ qO, short* __restrict__ kO, short* __restrict__ vT) {
  __shared__ __align__(16) short sm[32768];
  const int tid = threadIdx.x, lane = tid & 63, wid = tid >> 6;
  const int xcd = blockIdx.x & 7, kk = blockIdx.x >> 3;  // kk in [0,144)
  const int m0 = (xcd * 8 + (kk & 7)) * 128;
  const int n0 = (kk >> 3) * 128;
  const int wr = (wid >> 1) * 32, wc = (wid & 1) * 64;
  const int l15 = lane & 15, gw = lane >> 4;
  const int s_ = (l15 >> 1) & 3;
  const int ldst = tid * 8;

  int off0, off1;
  {
    int e = ldst;            int row = e >> 6;
    off0 = row * 768 + (((((e >> 3) & 7) ^ ((row >> 1) & 3))) << 3);
    e = 4096 + ldst;         row = e >> 6;
    off1 = row * 768 + (((((e >> 3) & 7) ^ ((row >> 1) & 3))) << 3);
  }
  const short* Ag = Xb + (size_t)m0 * 768;
  const short* Bg = Wqkv + (size_t)n0 * 768;

  const int src = n0 / 768;  // 0=q 1=k 2=v
  const int nloc = n0 % 768;
  float bias[4];
#pragma unroll
  for (int ni = 0; ni < 4; ++ni) {
    int c = nloc + wc + ni * 16 + l15;
    bias[ni] = (src == 0) ? bq[c] * QSCALE : (src == 1) ? bk[c] : bv[c];
  }
  WAIT0(); SBAR();

  f32x4 acc[2][4] = {};
  GEMM_CORE_512(Ag, Bg, acc);

  const int bb_ = m0 >> 12;
  const int s0 = m0 & (SEQ - 1);
  __syncthreads();
  if (src < 2) {
#pragma unroll
    for (int mi = 0; mi < 2; ++mi)
#pragma unroll
      for (int ni = 0; ni < 4; ++ni) {
        int row = wr + mi * 16 + ((lane >> 4) << 2);
        int col = wc + ni * 16 + l15;
#pragma unroll
        for (int r = 0; r < 4; ++r)
          sm[(row + r) * 132 + col] = f2bf(acc[mi][ni][r] + bias[ni]);
      }
    __syncthreads();
    short* dst = (src == 0) ? qO : kO;
    for (int u = tid; u < 8192; u += 512) {
      int r = u >> 6, cp = (u & 63) << 1;
      unsigned val = *(const unsigned*)&sm[r * 132 + cp];
      int c = nloc + cp;
      int h = c >> 6, d = c & 63;
      *(unsigned*)&dst[(((bb_ * NH + h) * SEQ) + s0 + r) * DH + d] = val;
    }
  } else {
#pragma unroll
    for (int mi = 0; mi < 2; ++mi)
#pragma unroll
      for (int ni = 0; ni < 4; ++ni) {
        int row = wr + mi * 16 + ((lane >> 4) << 2);
        int col = wc + ni * 16 + l15;
        short4 pk;
        pk.x = f2bf(acc[mi][ni][0] + bias[ni]);
        pk.y = f2bf(acc[mi][ni][1] + bias[ni]);
        pk.z = f2bf(acc[mi][ni][2] + bias[ni]);
        pk.w = f2bf(acc[mi][ni][3] + bias[ni]);
        *(short4*)&sm[col * 132 + row] = pk;
      }
    __syncthreads();
    for (int u = tid; u < 8192; u += 512) {
      int cc = u >> 6, rp = (u & 63) << 1;
      unsigned val = *(const unsigned*)&sm[cc * 132 + rp];
      int c = nloc + cc;
      int h = c >> 6, d = c & 63;
      *(unsigned*)&vT[(((bb_ * NH + h) * DH) + d) * SEQ + s0 + rp] = val;
    }
  }
}

// ---------------- sliding-window attention (R18/R20-exact) ----------------
__global__ __launch_bounds__(512, 4) void attn(
    const short* __restrict__ qI, const short* __restrict__ kI,
    const short* __restrict__ vT, const float* __restrict__ amask,
    short* __restrict__ ctx) {
  __shared__ __align__(16) short Ks[128 * 64];
  __shared__ __align__(16) short Vs[64 * 128];
  __shared__ __align__(16) short Ps[8][16 * 132];
  __shared__ __align__(16) float BiasL[768];
  const int tid = threadIdx.x, lane = tid & 63, wid = tid >> 6;
  const int vb_id = (blockIdx.x & 7) * 96 + (blockIdx.x >> 3);
  const int strip = vb_id & 31;
  const int hh = (vb_id >> 5) % 12;
  const int bb = vb_id / 384;
  const int s0 = strip * 128;
  const int n = s0 >> 8;
  const int i0 = s0 & 255;
  const int base = (n - 1) * 256;
  const int bh = bb * NH + hh;
  const int m = lane & 15, hq = lane >> 4;
  const int swz = m & 7;
  const int iw = i0 + (wid << 4);

  const short* qbase = qI + ((size_t)(bh * SEQ) + s0 + (wid << 4)) * DH;
  const bf16x8 aq0 = *(const bf16x8*)(qbase + m * DH + (hq << 3));
  const bf16x8 aq1 = *(const bf16x8*)(qbase + m * DH + 32 + (hq << 3));

  const int kb_s0 = m * 64 + ((hq ^ swz) << 3);
  const int kb_s1 = m * 64 + (((hq + 4) ^ swz) << 3);
  const int vk0 = m * 128 + ((hq ^ swz) << 3);
  const int vk1 = m * 128 + (((hq + 4) ^ swz) << 3);
  const int vk2 = m * 128 + (((hq + 8) ^ swz) << 3);
  const int vk3 = m * 128 + (((hq + 12) ^ swz) << 3);
  short* Pw = Ps[wid];
  const int pwr = m * 132;

  const int e0 = tid * 8, e1 = tid * 8 + 4096;
  const int kj0 = e0 >> 6, kj1 = e1 >> 6;
  const int ksrc0 = kj0 * DH + ((((e0 >> 3) & 7) ^ (kj0 & 7)) << 3);
  const int ksrc1 = kj1 * DH + ((((e1 >> 3) & 7) ^ (kj1 & 7)) << 3);
  const int vd0 = e0 >> 7, vd1 = e1 >> 7;
  const int vsrc0 = vd0 * SEQ + ((((e0 >> 3) & 15) ^ (vd0 & 7)) << 3);
  const int vsrc1 = vd1 * SEQ + ((((e1 >> 3) & 15) ^ (vd1 & 7)) << 3);

  const short* kg0 = kI + (size_t)bh * SEQ * DH;
  const short* vg0 = vT + (size_t)bh * DH * SEQ;

  if (tid < 192) {
    int idx = base + tid * 4;
    idx = idx < 0 ? 0 : (idx > SEQ - 4 ? SEQ - 4 : idx);
    float4 bv = *(const float4*)(amask + bb * SEQ + idx);
    bv.x *= -LOG2E; bv.y *= -LOG2E; bv.z *= -LOG2E; bv.w *= -LOG2E;
    *(float4*)&BiasL[tid * 4] = bv;
  }

  f32x4 acc[4] = {};
  float mrow = -1e30f, lrow = 0.f;

#pragma unroll 1
  for (int c = 0; c < 6; ++c) {
    const int j0 = c << 7;
    const int kpos0 = base + j0;
    if (kpos0 < 0 || kpos0 >= SEQ) continue;
    if (j0 + 127 < i0 || j0 > i0 + 639) continue;

    __syncthreads();
    {
      const short* kb = kg0 + (size_t)kpos0 * DH;
      gload16(kb + ksrc0, (short*)Ks + e0);
      gload16(kb + ksrc1, (short*)Ks + e1);
      const short* vbp = vg0 + kpos0;
      gload16(vbp + vsrc0, (short*)Vs + e0);
      gload16(vbp + vsrc1, (short*)Vs + e1);
    }
    __syncthreads();

    f32x4 sc[8];
    __builtin_amdgcn_s_setprio(1);
#pragma unroll
    for (int jt = 0; jt < 8; ++jt) {
      bf16x8 k0 = *(const bf16x8*)(Ks + jt * 1024 + kb_s0);
      bf16x8 k1 = *(const bf16x8*)(Ks + jt * 1024 + kb_s1);
      f32x4 z = {};
      z = mfma16(k0, aq0, z);
      z = mfma16(k1, aq1, z);
      sc[jt] = z;
    }
    __builtin_amdgcn_s_setprio(0);

    const float* mp = BiasL + j0 + (hq << 2);
    float mn_l = -3e38f;
    const bool interior = (j0 >= iw + 15) && (j0 <= iw + 385);
    if (interior) {
#pragma unroll
      for (int jt = 0; jt < 8; ++jt) {
        float4 b4 = *(const float4*)(mp + jt * 16);
#pragma unroll
        for (int r = 0; r < 4; ++r) {
          float s = sc[jt][r] + (&b4.x)[r];
          sc[jt][r] = s;
          mn_l = fmaxf(mn_l, s);
        }
      }
    } else {
      const int iq = iw + m;
#pragma unroll
      for (int jt = 0; jt < 8; ++jt) {
        float4 b4 = *(const float4*)(mp + jt * 16);
        const int jb = j0 + jt * 16 + (hq << 2);
#pragma unroll
        for (int r = 0; r < 4; ++r) {
          int j = jb + r;
          float s = sc[jt][r] + (&b4.x)[r];
          s = (j >= iq && j <= iq + 512) ? s : NEGV;
          sc[jt][r] = s;
          mn_l = fmaxf(mn_l, s);
        }
      }
    }

    if (__any(mn_l > mrow + 8.0f)) {
      float mn = fmaxf(mrow, mn_l);
      mn = fmaxf(mn, __shfl_xor(mn, 16));
      mn = fmaxf(mn, __shfl_xor(mn, 32));
      const float scl = exp2f(mrow - mn);
      mrow = mn;
      lrow *= scl;
      const float s0r = __shfl(scl, (hq << 2) + 0);
      const float s1r = __shfl(scl, (hq << 2) + 1);
      const float s2r = __shfl(scl, (hq << 2) + 2);
      const float s3r = __shfl(scl, (hq << 2) + 3);
#pragma unroll
      for (int nt = 0; nt < 4; ++nt) {
        acc[nt][0] *= s0r; acc[nt][1] *= s1r;
        acc[nt][2] *= s2r; acc[nt][3] *= s3r;
      }
    }

    float l0 = 0.f;
#pragma unroll
    for (int jt = 0; jt < 8; ++jt) {
      float p0 = exp2f(sc[jt][0] - mrow);
      float p1 = exp2f(sc[jt][1] - mrow);
      float p2 = exp2f(sc[jt][2] - mrow);
      float p3 = exp2f(sc[jt][3] - mrow);
      l0 += (p0 + p1) + (p2 + p3);
      uint2 u;
      u.x = pack2bf_rnd(p0, p1);
      u.y = pack2bf_rnd(p2, p3);
      *(uint2*)(Pw + pwr + jt * 16 + (hq << 2)) = u;
    }
    lrow += l0;

    asm volatile("s_waitcnt lgkmcnt(0)" ::: "memory");
    __builtin_amdgcn_sched_barrier(0);

    __builtin_amdgcn_s_setprio(1);
#pragma unroll
    for (int ks = 0; ks < 4; ++ks) {
      bf16x8 pa = *(const bf16x8*)(Pw + pwr + ks * 32 + (hq << 3));
      const int vkk = (ks == 0) ? vk0 : (ks == 1) ? vk1 : (ks == 2) ? vk2 : vk3;
#pragma unroll
      for (int nt = 0; nt < 4; ++nt) {
        bf16x8 vv = *(const bf16x8*)(Vs + nt * 2048 + vkk);
        acc[nt] = mfma16(pa, vv, acc[nt]);
      }
    }
    __builtin_amdgcn_s_setprio(0);
  }

  lrow += __shfl_xor(lrow, 16);
  lrow += __shfl_xor(lrow, 32);
  const float inv = 1.0f / lrow;
  const float i0r = __shfl(inv, (hq << 2) + 0);
  const float i1r = __shfl(inv, (hq << 2) + 1);
  const float i2r = __shfl(inv, (hq << 2) + 2);
  const float i3r = __shfl(inv, (hq << 2) + 3);
#pragma unroll
  for (int nt = 0; nt < 4; ++nt) {
    Pw[((hq << 2) + 0) * 72 + nt * 16 + m] = f2bf(acc[nt][0] * i0r);
    Pw[((hq << 2) + 1) * 72 + nt * 16 + m] = f2bf(acc[nt][1] * i1r);
    Pw[((hq << 2) + 2) * 72 + nt * 16 + m] = f2bf(acc[nt][2] * i2r);
    Pw[((hq << 2) + 3) * 72 + nt * 16 + m] = f2bf(acc[nt][3] * i3r);
  }
  asm volatile("s_waitcnt lgkmcnt(0)" ::: "memory");
  __builtin_amdgcn_sched_barrier(0);
#pragma unroll
  for (int it = 0; it < 2; ++it) {
    int row = it * 8 + (lane >> 3);
    bf16x8 val = *(const bf16x8*)(Pw + row * 72 + ((lane & 7) << 3));
    *(bf16x8*)(ctx + ((size_t)(bb * SEQ) + s0 + (wid << 4) + row) * DM +
               hh * DH + ((lane & 7) << 3)) = val;
  }
}

// ---------------- output projection GEMM (512 threads, R21 core) ----------
__global__ __launch_bounds__(512) void gemm_out(
    const short* __restrict__ Cb, const short* __restrict__ Wob,
    const float* __restrict__ bo, float* __restrict__ out) {
  __shared__ __align__(16) short sm[32768];
  const int tid = threadIdx.x, lane = tid & 63, wid = tid >> 6;
  const int xcd = blockIdx.x & 7, kk = blockIdx.x >> 3;  // kk in [0,48)
  const int m0 = (xcd * 8 + (kk & 7)) * 128;
  const int n0 = (kk >> 3) * 128;
  const int wr = (wid >> 1) * 32, wc = (wid & 1) * 64;
  const int l15 = lane & 15, gw = lane >> 4;
  const int s_ = (l15 >> 1) & 3;
  const int ldst = tid * 8;

  int off0, off1;
  {
    int e = ldst;            int row = e >> 6;
    off0 = row * 768 + (((((e >> 3) & 7) ^ ((row >> 1) & 3))) << 3);
    e = 4096 + ldst;         row = e >> 6;
    off1 = row * 768 + (((((e >> 3) & 7) ^ ((row >> 1) & 3))) << 3);
  }
  const short* Ag = Cb + (size_t)m0 * 768;
  const short* Bg = Wob + (size_t)n0 * 768;

  float bias[4];
#pragma unroll
  for (int ni = 0; ni < 4; ++ni)
    bias[ni] = bo[n0 + wc + ni * 16 + l15];
  WAIT0(); SBAR();

  f32x4 acc[2][4] = {};
  GEMM_CORE_512(Ag, Bg, acc);

#pragma unroll
  for (int mi = 0; mi < 2; ++mi)
#pragma unroll
    for (int ni = 0; ni < 4; ++ni) {
      int row = m0 + wr + mi * 16 + ((lane >> 4) << 2);
      int col = n0 + wc + ni * 16 + l15;
#pragma unroll
      for (int r = 0; r < 4; ++r)
        out[(row + r) * DM + col] = acc[mi][ni][r] + bias[ni];
    }
}

// ---------------- launcher ----------------
extern "C" void kernel_launch(void* const* d_in, const int* in_sizes, int n_in,
                              void* d_out, int out_size, void* d_ws, size_t ws_size,
                              hipStream_t stream) {
  (void)in_sizes; (void)n_in; (void)out_size; (void)ws_size;
  const float* hs    = (const float*)d_in[0];
  const float* amask = (const float*)d_in[1];
  const float* Wq = (const float*)d_in[2];
  const float* bq = (const float*)d_in[3];
  const float* Wk = (const float*)d_in[4];
  const float* bk = (const float*)d_in[5];
  const float* Wv = (const float*)d_in[6];
  const float* bv = (const float*)d_in[7];
  const float* Wo = (const float*)d_in[8];
  const float* bo = (const float*)d_in[9];
  float* out = (float*)d_out;
  char* ws = (char*)d_ws;
  short* Xb   = (short*)(ws);
  short* Wqkv = (short*)(ws + 12582912);
  short* Wob  = (short*)(ws + 16121856);
  short* qB   = (short*)(ws + 17301504);
  short* kB   = (short*)(ws + 29884416);
  short* vTB  = (short*)(ws + 42467328);
  short* ctx  = Xb;  // Xb dead after gemm_qkv

  cvt_all<<<dim3(8448), dim3(256), 0, stream>>>(hs, Xb, Wq, Wk, Wv, Wo, Wqkv, Wob);
  gemm_qkv<<<dim3(1152), dim3(512), 0, stream>>>(Xb, Wqkv, bq, bk, bv, qB, kB, vTB);
  attn<<<dim3(768), dim3(512), 0, stream>>>(qB, kB, vTB, amask, ctx);
  gemm_out<<<dim3(384), dim3(512), 0, stream>>>(ctx, Wob, bo, out);
}